// Round 8
// baseline (996.284 us; speedup 1.0000x reference)
//
#include <hip/hip_runtime.h>
#include <hip/hip_fp16.h>

#define NPT 4096
#define DM 128
#define INF64 0xFFFFFFFFFFFFFFFFull
#define INF32 0xFFFFFFFFu

typedef _Float16 f16x8 __attribute__((ext_vector_type(8)));
typedef _Float16 f16x2 __attribute__((ext_vector_type(2)));
typedef float f32x4 __attribute__((ext_vector_type(4)));

static __device__ __forceinline__ unsigned long long make_key64(unsigned key, unsigned node) {
    unsigned h = key >> 16, j = key & 0xFFFFu;
    unsigned mn = node < j ? node : j;
    unsigned mx = node < j ? j : node;
    return ((unsigned long long)h << 48) | ((unsigned long long)mn << 32) |
           ((unsigned long long)mx << 16) | (unsigned long long)j;
}

// ---------------- init ----------------
__global__ __launch_bounds__(256) void init_kernel(unsigned* __restrict__ comp,
                                                   unsigned long long* __restrict__ compbest,
                                                   float* __restrict__ w,
                                                   unsigned* __restrict__ cnt,
                                                   float* __restrict__ rep) {
    int i = blockIdx.x * blockDim.x + threadIdx.x;   // 0..8191
    comp[i] = (unsigned)(i & (NPT - 1));
    compbest[i] = INF64;
    w[i] = 0.0f;
    if (i < 2) cnt[i] = 0u;
    if (i == 0) rep[0] = 0.0f;
}

// ---------------- prep: fp32 -> fp16 rows + consistent squared norms ----------------
__global__ __launch_bounds__(256) void prep_kernel(const float* __restrict__ x1,
                                                   const float* __restrict__ x2,
                                                   _Float16* __restrict__ Xh,
                                                   float* __restrict__ norms) {
    const int wv = threadIdx.x >> 6, ln = threadIdx.x & 63;
    const int row = blockIdx.x * 4 + wv;             // 0..8191
    const float* src = (row < NPT) ? (x1 + (size_t)row * DM)
                                   : (x2 + (size_t)(row - NPT) * DM);
    float2 v = *(const float2*)(src + ln * 2);
    _Float16 h0 = (_Float16)v.x, h1 = (_Float16)v.y;
    f16x2 p; p[0] = h0; p[1] = h1;
    *(f16x2*)(Xh + (size_t)row * DM + ln * 2) = p;
    float a = (float)h0, b = (float)h1;
    float s = a * a + b * b;
    #pragma unroll
    for (int off = 32; off > 0; off >>= 1) s += __shfl_down(s, off);
    if (ln == 0) norms[row] = s;
}

// ---------------- Gram via fp16 MFMA, LDS-staged coalesced writes ----------------
__global__ __launch_bounds__(256) void gram_kernel(const _Float16* __restrict__ Xh,
                                                   const float* __restrict__ norms,
                                                   __half* __restrict__ Dall) {
    const int mat = blockIdx.y;
    const _Float16* __restrict__ X = Xh + (size_t)mat * NPT * DM;
    const float* __restrict__ nrm = norms + mat * NPT;
    __half* __restrict__ D = Dall + (size_t)mat * NPT * NPT;

    const int I = blockIdx.x >> 5;
    const int J = blockIdx.x & 31;

    __shared__ _Float16 tile[128 * 136];

    const int t = threadIdx.x;
    const int wv = t >> 6, ln = t & 63;
    const int rloc = (wv >> 1) * 64;
    const int cloc = (wv & 1) * 64;
    const int rowBase = I * 128 + rloc;
    const int colBase = J * 128 + cloc;
    const int lr = ln & 15;
    const int kg = ln >> 4;

    f32x4 acc[4][4];
    #pragma unroll
    for (int m = 0; m < 4; ++m)
        #pragma unroll
        for (int n = 0; n < 4; ++n)
            acc[m][n] = (f32x4){0.f, 0.f, 0.f, 0.f};

    #pragma unroll
    for (int ks = 0; ks < 4; ++ks) {
        const int k0 = ks * 32 + kg * 8;
        f16x8 a[4], b[4];
        #pragma unroll
        for (int m = 0; m < 4; ++m)
            a[m] = *(const f16x8*)(X + (size_t)(rowBase + m * 16 + lr) * DM + k0);
        #pragma unroll
        for (int n = 0; n < 4; ++n)
            b[n] = *(const f16x8*)(X + (size_t)(colBase + n * 16 + lr) * DM + k0);
        #pragma unroll
        for (int m = 0; m < 4; ++m)
            #pragma unroll
            for (int n = 0; n < 4; ++n)
                acc[m][n] = __builtin_amdgcn_mfma_f32_16x16x32_f16(a[m], b[n], acc[m][n], 0, 0, 0);
    }

    float nr[16], nc[4];
    #pragma unroll
    for (int m = 0; m < 4; ++m)
        #pragma unroll
        for (int q = 0; q < 4; ++q)
            nr[m * 4 + q] = nrm[rowBase + m * 16 + kg * 4 + q];
    #pragma unroll
    for (int n = 0; n < 4; ++n) nc[n] = nrm[colBase + n * 16 + lr];

    #pragma unroll
    for (int m = 0; m < 4; ++m) {
        #pragma unroll
        for (int n = 0; n < 4; ++n) {
            #pragma unroll
            for (int q = 0; q < 4; ++q) {
                const int rl = rloc + m * 16 + kg * 4 + q;
                const int cl = cloc + n * 16 + lr;
                float d2 = nr[m * 4 + q] + nc[n] - 2.0f * acc[m][n][q];
                float d = sqrtf(fmaxf(d2, 0.0f) + 1e-12f);
                tile[rl * 136 + cl] = (_Float16)d;
            }
        }
    }
    __syncthreads();

    const int tileRow0 = I * 128;
    #pragma unroll
    for (int it = 0; it < 8; ++it) {
        int idx = it * 256 + t;
        int row = idx >> 4;
        int ch = idx & 15;
        *(uint4*)(&D[(size_t)(tileRow0 + row) * NPT + J * 128 + ch * 8]) =
            *(const uint4*)(&tile[row * 136 + ch * 8]);
    }
}

// ---------------- round 0: full scan, exact per-node top-8 cache + compbest ----------------
// grid (NPT/16, 2), block 1024; one wave per row. All nodes are singleton comps:
// everything except self is foreign -> no comp staging, no atomics (one writer/slot).
__global__ __launch_bounds__(1024) void boruvka0(const __half* __restrict__ Dall,
                                                 unsigned* __restrict__ cacheAll,
                                                 unsigned long long* __restrict__ compbestAll) {
    const int mat = blockIdx.y;
    const __half* __restrict__ D = Dall + (size_t)mat * NPT * NPT;
    unsigned* __restrict__ cache = cacheAll + (size_t)mat * NPT * 8;
    unsigned long long* __restrict__ compbest = compbestAll + mat * NPT;

    const int t = threadIdx.x, wv = t >> 6, ln = t & 63;
    const int node = blockIdx.x * 16 + wv;
    const unsigned* __restrict__ row = (const unsigned*)(D + (size_t)node * NPT);

    unsigned k8[8];
    #pragma unroll
    for (int s = 0; s < 8; ++s) k8[s] = INF32;

    #pragma unroll
    for (int k = 0; k < 8; ++k) {
        const int jb = k * 512 + ln * 8;
        uint4 dv = *(const uint4*)(row + (jb >> 1));
        const unsigned dp[4] = {dv.x, dv.y, dv.z, dv.w};
        #pragma unroll
        for (int q = 0; q < 4; ++q) {
            int j0 = jb + q * 2;
            unsigned kk0 = (dp[q] << 16) | (unsigned)j0;
            unsigned kk1 = (dp[q] & 0xFFFF0000u) | (unsigned)(j0 + 1);
            if (j0 == node) kk0 = INF32;
            if (j0 + 1 == node) kk1 = INF32;
            if (kk0 < k8[7]) {
                unsigned cur = kk0;
                #pragma unroll
                for (int s = 0; s < 8; ++s) {
                    unsigned mn = cur < k8[s] ? cur : k8[s];
                    unsigned mx = cur < k8[s] ? k8[s] : cur;
                    k8[s] = mn; cur = mx;
                }
            }
            if (kk1 < k8[7]) {
                unsigned cur = kk1;
                #pragma unroll
                for (int s = 0; s < 8; ++s) {
                    unsigned mn = cur < k8[s] ? cur : k8[s];
                    unsigned mx = cur < k8[s] ? k8[s] : cur;
                    k8[s] = mn; cur = mx;
                }
            }
        }
    }

    // butterfly merge across 64 lanes: keep smallest 8, re-sort (bitonic-8)
    #pragma unroll
    for (int off = 1; off < 64; off <<= 1) {
        unsigned b[8], c[8];
        #pragma unroll
        for (int s = 0; s < 8; ++s) b[s] = __shfl_xor(k8[s], off);
        #pragma unroll
        for (int s = 0; s < 8; ++s) {
            unsigned x = k8[s], y = b[7 - s];
            c[s] = x < y ? x : y;
        }
        #define CE(i, j) { unsigned mn = c[i] < c[j] ? c[i] : c[j]; \
                           unsigned mx = c[i] < c[j] ? c[j] : c[i]; c[i] = mn; c[j] = mx; }
        CE(0,4) CE(1,5) CE(2,6) CE(3,7)
        CE(0,2) CE(1,3) CE(4,6) CE(5,7)
        CE(0,1) CE(2,3) CE(4,5) CE(6,7)
        #undef CE
        #pragma unroll
        for (int s = 0; s < 8; ++s) k8[s] = c[s];
    }

    // lanes 0..7 store the sorted top-8 (coalesced); lane 0 stores compbest
    unsigned sel = k8[0];
    #pragma unroll
    for (int s = 1; s < 8; ++s) sel = (ln == s) ? k8[s] : sel;
    if (ln < 8) cache[(size_t)node * 8 + ln] = sel;
    if (ln == 0) compbest[node] = make_key64(k8[0], (unsigned)node);
}

// ---------------- Boruvka phase C+D for round 0 (global arrays) ----------------
__global__ __launch_bounds__(1024) void boruvka_cd(unsigned* __restrict__ compAll,
                                                   unsigned long long* __restrict__ compbestAll,
                                                   float* __restrict__ wAll,
                                                   unsigned* __restrict__ cntAll) {
    const int mat = blockIdx.x;
    unsigned* __restrict__ comp = compAll + mat * NPT;
    unsigned long long* __restrict__ compbest = compbestAll + mat * NPT;
    float* __restrict__ w = wAll + mat * NPT;
    unsigned* __restrict__ cnt = cntAll + mat;

    __shared__ unsigned short par[NPT];
    const int t = threadIdx.x;

    for (int c = t; c < NPT; c += 1024) {
        unsigned p = (unsigned)c;
        unsigned long long key = compbest[c];
        if (comp[c] == (unsigned)c && key != INF64) {
            unsigned jout = (unsigned)(key & 0xFFFFull);
            unsigned c2 = comp[jout];
            unsigned long long k2 = compbest[c2];
            bool mutual = (k2 >> 16) == (key >> 16);
            if (!mutual || (unsigned)c < c2) {
                unsigned short hb = (unsigned short)(key >> 48);
                float wv = fminf(__half2float(__ushort_as_half(hb)), 100.0f);
                unsigned slot = atomicAdd(cnt, 1u);
                w[slot] = wv;
            }
            p = (mutual && (unsigned)c < c2) ? (unsigned)c : c2;
        }
        par[c] = (unsigned short)p;
    }
    __syncthreads();

    for (int it = 0; it < 12; ++it) {
        unsigned short np[4];
        #pragma unroll
        for (int q = 0; q < 4; ++q) np[q] = par[par[t + q * 1024]];
        __syncthreads();
        #pragma unroll
        for (int q = 0; q < 4; ++q) par[t + q * 1024] = np[q];
        __syncthreads();
    }

    for (int c = t; c < NPT; c += 1024) comp[c] = par[comp[c]];
}

// ---------------- all remaining rounds: one block per matrix, state in LDS ----------------
__global__ __launch_bounds__(1024) void mst_finish(const __half* __restrict__ Dall,
                                                   const unsigned* __restrict__ cacheAll,
                                                   const unsigned* __restrict__ compAll,
                                                   float* __restrict__ wAll,
                                                   const unsigned* __restrict__ cntAll) {
    const int mat = blockIdx.x;
    const __half* __restrict__ D = Dall + (size_t)mat * NPT * NPT;
    const unsigned* __restrict__ cache = cacheAll + (size_t)mat * NPT * 8;
    const unsigned* __restrict__ comp = compAll + mat * NPT;
    float* __restrict__ w = wAll + mat * NPT;

    __shared__ unsigned short lcomp[NPT];          // 8 KB
    __shared__ unsigned short par[NPT];            // 8 KB
    __shared__ unsigned long long cbest[NPT];      // 32 KB
    __shared__ unsigned short flist[NPT];          // 8 KB
    __shared__ unsigned counters[2];               // [0]=nfallback, [1]=edges this round

    const int t = threadIdx.x, wv = t >> 6, ln = t & 63;
    for (int i = t; i < NPT; i += 1024) lcomp[i] = (unsigned short)comp[i];
    unsigned cnt = cntAll[mat];
    __syncthreads();

    for (int round = 0; round < 20; ++round) {
        if (cnt >= NPT - 1u) break;

        for (int i = t; i < NPT; i += 1024) cbest[i] = INF64;
        if (t == 0) { counters[0] = 0u; counters[1] = 0u; }
        __syncthreads();

        // ---- A: scan top-8 cache; first foreign entry is the exact row-min foreign edge ----
        for (int nd = t; nd < NPT; nd += 1024) {
            uint4 c0 = *(const uint4*)(cache + (size_t)nd * 8);
            uint4 c1 = *(const uint4*)(cache + (size_t)nd * 8 + 4);
            const unsigned e[8] = {c0.x, c0.y, c0.z, c0.w, c1.x, c1.y, c1.z, c1.w};
            const unsigned ci = lcomp[nd];
            unsigned found = INF32;
            #pragma unroll
            for (int q = 0; q < 8; ++q) {
                if (found == INF32 && lcomp[e[q] & 0xFFFFu] != ci) found = e[q];
            }
            if (found != INF32)
                atomicMin(&cbest[ci], make_key64(found, (unsigned)nd));
            else
                flist[atomicAdd(&counters[0], 1u)] = (unsigned short)nd;
        }
        __syncthreads();

        // ---- B: exact fallback — full-row rescan for nodes whose whole top-8 is internal ----
        const unsigned nf = counters[0];
        for (unsigned fi = (unsigned)wv; fi < nf; fi += 16) {
            const int node = flist[fi];
            const unsigned ci = lcomp[node];
            const unsigned* __restrict__ row = (const unsigned*)(D + (size_t)node * NPT);
            unsigned best = INF32;
            #pragma unroll
            for (int k = 0; k < 8; ++k) {
                const int jb = k * 512 + ln * 8;
                uint4 dv = *(const uint4*)(row + (jb >> 1));
                uint4 cv = *(const uint4*)&lcomp[jb];
                const unsigned dp[4] = {dv.x, dv.y, dv.z, dv.w};
                const unsigned cp[4] = {cv.x, cv.y, cv.z, cv.w};
                #pragma unroll
                for (int q = 0; q < 4; ++q) {
                    int j0 = jb + q * 2;
                    unsigned kk0 = (dp[q] << 16) | (unsigned)j0;
                    unsigned kk1 = (dp[q] & 0xFFFF0000u) | (unsigned)(j0 + 1);
                    if ((cp[q] & 0xFFFFu) == ci) kk0 = INF32;
                    if ((cp[q] >> 16) == ci)     kk1 = INF32;
                    unsigned m = kk0 < kk1 ? kk0 : kk1;
                    best = best < m ? best : m;
                }
            }
            #pragma unroll
            for (int off = 32; off > 0; off >>= 1) {
                unsigned o = __shfl_down(best, off);
                best = best < o ? best : o;
            }
            if (ln == 0 && best != INF32)
                atomicMin(&cbest[ci], make_key64(best, (unsigned)node));
        }
        __syncthreads();

        // ---- CD: union roots, collect weights, pointer-jump, relabel ----
        for (int c = t; c < NPT; c += 1024) {
            unsigned p = (unsigned)c;
            if (lcomp[c] == (unsigned short)c) {
                unsigned long long key = cbest[c];
                if (key != INF64) {
                    unsigned jout = (unsigned)(key & 0xFFFFull);
                    unsigned c2 = lcomp[jout];
                    unsigned long long k2 = cbest[c2];
                    bool mutual = (k2 >> 16) == (key >> 16);
                    if (!mutual || (unsigned)c < c2) {
                        unsigned short hb = (unsigned short)(key >> 48);
                        float wvv = fminf(__half2float(__ushort_as_half(hb)), 100.0f);
                        unsigned slot = atomicAdd(&counters[1], 1u);
                        w[cnt + slot] = wvv;
                    }
                    p = (mutual && (unsigned)c < c2) ? (unsigned)c : c2;
                }
            }
            par[c] = (unsigned short)p;
        }
        __syncthreads();

        for (int it = 0; it < 12; ++it) {
            unsigned short np[4];
            #pragma unroll
            for (int q = 0; q < 4; ++q) np[q] = par[par[t + q * 1024]];
            __syncthreads();
            #pragma unroll
            for (int q = 0; q < 4; ++q) par[t + q * 1024] = np[q];
            __syncthreads();
        }

        for (int c = t; c < NPT; c += 1024) lcomp[c] = par[lcomp[c]];
        __syncthreads();
        cnt += counters[1];
        __syncthreads();   // protect counters/cbest before next round's reset
    }
}

// ---------------- representation loss partial sums ----------------
__global__ __launch_bounds__(256) void rep_kernel(const float4* __restrict__ x1,
                                                  const float4* __restrict__ x2,
                                                  float* __restrict__ acc) {
    int idx = blockIdx.x * blockDim.x + threadIdx.x;
    int stride = gridDim.x * blockDim.x;
    float s = 0.f;
    for (int i = idx; i < NPT * DM / 4; i += stride) {
        float4 a = x1[i], b = x2[i];
        float d0 = a.x - b.x, d1 = a.y - b.y, d2 = a.z - b.z, d3 = a.w - b.w;
        s += d0 * d0 + d1 * d1 + d2 * d2 + d3 * d3;
    }
    #pragma unroll
    for (int off = 32; off > 0; off >>= 1) s += __shfl_down(s, off);
    __shared__ float partial[4];
    int wv = threadIdx.x >> 6, ln = threadIdx.x & 63;
    if (ln == 0) partial[wv] = s;
    __syncthreads();
    if (threadIdx.x == 0) {
        float tot = partial[0] + partial[1] + partial[2] + partial[3];
        atomicAdd(acc, tot);
    }
}

// ---------------- sort one weight array per block (bitonic, LDS) ----------------
__global__ __launch_bounds__(1024) void sort_kernel(float* __restrict__ wAll) {
    float* __restrict__ w = wAll + blockIdx.x * NPT;
    __shared__ float s[NPT];
    const int t = threadIdx.x;
    for (int i = t; i < NPT; i += 1024) s[i] = w[i];
    __syncthreads();

    for (int k = 2; k <= NPT; k <<= 1) {
        for (int j = k >> 1; j > 0; j >>= 1) {
            for (int i = t; i < NPT; i += 1024) {
                int ixj = i ^ j;
                if (ixj > i) {
                    bool up = (i & k) == 0;
                    float a = s[i], b = s[ixj];
                    if ((a > b) == up) { s[i] = b; s[ixj] = a; }
                }
            }
            __syncthreads();
        }
    }
    for (int i = t; i < NPT; i += 1024) w[i] = s[i];
}

// ---------------- W1 diff-sum + combine ----------------
__global__ __launch_bounds__(1024) void final2_kernel(const float* __restrict__ w,
                                                      const float* __restrict__ rep,
                                                      float* __restrict__ out) {
    const int t = threadIdx.x;
    float loc = 0.f;
    for (int i = t; i < NPT; i += 1024) loc += fabsf(w[i] - w[NPT + i]);
    #pragma unroll
    for (int off = 32; off > 0; off >>= 1) loc += __shfl_down(loc, off);
    __shared__ float reds[16];
    int wv = t >> 6, ln = t & 63;
    if (ln == 0) reds[wv] = loc;
    __syncthreads();
    if (t == 0) {
        float tot = 0.f;
        #pragma unroll
        for (int i = 0; i < 16; ++i) tot += reds[i];
        out[0] = tot + rep[0] * (1.0f / (NPT * DM));
    }
}

extern "C" void kernel_launch(void* const* d_in, const int* in_sizes, int n_in,
                              void* d_out, int out_size, void* d_ws, size_t ws_size,
                              hipStream_t stream) {
    const float* x1 = (const float*)d_in[0];
    const float* x2 = (const float*)d_in[1];
    float* out = (float*)d_out;

    char* ws = (char*)d_ws;
    __half* D = (__half*)ws;                                           // 64 MB
    size_t off = (size_t)2 * NPT * NPT * sizeof(__half);
    _Float16* Xh = (_Float16*)(ws + off);                              // 2 MB
    off += (size_t)2 * NPT * DM * sizeof(_Float16);
    float* norms = (float*)(ws + off);                                 // 32 KB
    off += (size_t)2 * NPT * sizeof(float);
    unsigned long long* compbest = (unsigned long long*)(ws + off);    // 64 KB
    off += (size_t)2 * NPT * sizeof(unsigned long long);
    float* w = (float*)(ws + off);                                     // 32 KB
    off += (size_t)2 * NPT * sizeof(float);
    unsigned* comp = (unsigned*)(ws + off);                            // 32 KB
    off += (size_t)2 * NPT * sizeof(unsigned);
    unsigned* cache = (unsigned*)(ws + off);                           // 256 KB
    off += (size_t)2 * NPT * 8 * sizeof(unsigned);
    unsigned* cnt = (unsigned*)(ws + off);                             // 8 B
    off += 2 * sizeof(unsigned);
    float* rep = (float*)(ws + off);

    init_kernel<<<2 * NPT / 256, 256, 0, stream>>>(comp, compbest, w, cnt, rep);

    prep_kernel<<<2 * NPT / 4, 256, 0, stream>>>(x1, x2, Xh, norms);

    gram_kernel<<<dim3(1024, 2), 256, 0, stream>>>(Xh, norms, D);

    boruvka0<<<dim3(NPT / 16, 2), 1024, 0, stream>>>(D, cache, compbest);

    boruvka_cd<<<2, 1024, 0, stream>>>(comp, compbest, w, cnt);

    mst_finish<<<2, 1024, 0, stream>>>(D, cache, comp, w, cnt);

    rep_kernel<<<256, 256, 0, stream>>>((const float4*)x1, (const float4*)x2, rep);

    sort_kernel<<<2, 1024, 0, stream>>>(w);

    final2_kernel<<<1, 1024, 0, stream>>>(w, rep, out);
}

// Round 9
// 363.488 us; speedup vs baseline: 2.7409x; 2.7409x over previous
//
#include <hip/hip_runtime.h>
#include <hip/hip_fp16.h>

#define NPT 4096
#define DM 128
#define ROUNDS 12
#define INF64 0xFFFFFFFFFFFFFFFFull
#define INF32 0xFFFFFFFFu

typedef _Float16 f16x8 __attribute__((ext_vector_type(8)));
typedef _Float16 f16x2 __attribute__((ext_vector_type(2)));
typedef float f32x4 __attribute__((ext_vector_type(4)));

static __device__ __forceinline__ unsigned long long make_key64(unsigned key, unsigned node) {
    unsigned h = key >> 16, j = key & 0xFFFFu;
    unsigned mn = node < j ? node : j;
    unsigned mx = node < j ? j : node;
    return ((unsigned long long)h << 48) | ((unsigned long long)mn << 32) |
           ((unsigned long long)mx << 16) | (unsigned long long)j;
}

// ---------------- init ----------------
__global__ __launch_bounds__(256) void init_kernel(unsigned* __restrict__ comp,
                                                   unsigned long long* __restrict__ compbest,
                                                   float* __restrict__ w,
                                                   unsigned* __restrict__ cnt,
                                                   float* __restrict__ rep) {
    int i = blockIdx.x * blockDim.x + threadIdx.x;   // 0..8191
    comp[i] = (unsigned)(i & (NPT - 1));
    compbest[i] = INF64;
    w[i] = 0.0f;
    if (i < 2) cnt[i] = 0u;
    if (i == 0) rep[0] = 0.0f;
}

// ---------------- prep: fp32 -> fp16 rows + consistent norms + rep-loss partials ----------------
// grid NPT/4 blocks x 256; wave handles row r of BOTH x1 and x2
__global__ __launch_bounds__(256) void prep_kernel(const float* __restrict__ x1,
                                                   const float* __restrict__ x2,
                                                   _Float16* __restrict__ Xh,
                                                   float* __restrict__ norms,
                                                   float* __restrict__ rep) {
    const int wv = threadIdx.x >> 6, ln = threadIdx.x & 63;
    const int row = blockIdx.x * 4 + wv;             // 0..4095
    float2 v1 = *(const float2*)(x1 + (size_t)row * DM + ln * 2);
    float2 v2 = *(const float2*)(x2 + (size_t)row * DM + ln * 2);
    _Float16 a0 = (_Float16)v1.x, a1 = (_Float16)v1.y;
    _Float16 b0 = (_Float16)v2.x, b1 = (_Float16)v2.y;
    f16x2 pa; pa[0] = a0; pa[1] = a1;
    f16x2 pb; pb[0] = b0; pb[1] = b1;
    *(f16x2*)(Xh + (size_t)row * DM + ln * 2) = pa;
    *(f16x2*)(Xh + (size_t)(NPT + row) * DM + ln * 2) = pb;

    float s1 = (float)a0 * (float)a0 + (float)a1 * (float)a1;
    float s2 = (float)b0 * (float)b0 + (float)b1 * (float)b1;
    float dx = v1.x - v2.x, dy = v1.y - v2.y;
    float rs = dx * dx + dy * dy;
    #pragma unroll
    for (int off = 32; off > 0; off >>= 1) {
        s1 += __shfl_down(s1, off);
        s2 += __shfl_down(s2, off);
        rs += __shfl_down(rs, off);
    }
    __shared__ float partial[4];
    if (ln == 0) {
        norms[row] = s1;
        norms[NPT + row] = s2;
        partial[wv] = rs;
    }
    __syncthreads();
    if (threadIdx.x == 0)
        atomicAdd(rep, partial[0] + partial[1] + partial[2] + partial[3]);
}

// ---------------- Gram via fp16 MFMA + fused exact 1-NN (round-0 phase A) ----------------
// grid (1024, 2), block 256
__global__ __launch_bounds__(256) void gram_kernel(const _Float16* __restrict__ Xh,
                                                   const float* __restrict__ norms,
                                                   __half* __restrict__ Dall,
                                                   unsigned long long* __restrict__ compbestAll) {
    const int mat = blockIdx.y;
    const _Float16* __restrict__ X = Xh + (size_t)mat * NPT * DM;
    const float* __restrict__ nrm = norms + mat * NPT;
    __half* __restrict__ D = Dall + (size_t)mat * NPT * NPT;
    unsigned long long* __restrict__ compbest = compbestAll + mat * NPT;

    const int I = blockIdx.x >> 5;
    const int J = blockIdx.x & 31;

    __shared__ __half tile[128 * 136];

    const int t = threadIdx.x;
    const int wv = t >> 6, ln = t & 63;
    const int rloc = (wv >> 1) * 64;
    const int cloc = (wv & 1) * 64;
    const int rowBase = I * 128 + rloc;
    const int colBase = J * 128 + cloc;
    const int lr = ln & 15;
    const int kg = ln >> 4;

    f32x4 acc[4][4];
    #pragma unroll
    for (int m = 0; m < 4; ++m)
        #pragma unroll
        for (int n = 0; n < 4; ++n)
            acc[m][n] = (f32x4){0.f, 0.f, 0.f, 0.f};

    #pragma unroll
    for (int ks = 0; ks < 4; ++ks) {
        const int k0 = ks * 32 + kg * 8;
        f16x8 a[4], b[4];
        #pragma unroll
        for (int m = 0; m < 4; ++m)
            a[m] = *(const f16x8*)(X + (size_t)(rowBase + m * 16 + lr) * DM + k0);
        #pragma unroll
        for (int n = 0; n < 4; ++n)
            b[n] = *(const f16x8*)(X + (size_t)(colBase + n * 16 + lr) * DM + k0);
        #pragma unroll
        for (int m = 0; m < 4; ++m)
            #pragma unroll
            for (int n = 0; n < 4; ++n)
                acc[m][n] = __builtin_amdgcn_mfma_f32_16x16x32_f16(a[m], b[n], acc[m][n], 0, 0, 0);
    }

    float nr[16], nc[4];
    #pragma unroll
    for (int m = 0; m < 4; ++m)
        #pragma unroll
        for (int q = 0; q < 4; ++q)
            nr[m * 4 + q] = nrm[rowBase + m * 16 + kg * 4 + q];
    #pragma unroll
    for (int n = 0; n < 4; ++n) nc[n] = nrm[colBase + n * 16 + lr];

    // C/D layout: col = lane&15, row = (lane>>4)*4 + reg
    #pragma unroll
    for (int m = 0; m < 4; ++m) {
        #pragma unroll
        for (int q = 0; q < 4; ++q) {
            const int rl = rloc + m * 16 + kg * 4 + q;
            const int rglob = I * 128 + rl;
            unsigned best = INF32;
            #pragma unroll
            for (int n = 0; n < 4; ++n) {
                const int cl = cloc + n * 16 + lr;
                const int cglob = J * 128 + cl;
                float d2 = nr[m * 4 + q] + nc[n] - 2.0f * acc[m][n][q];
                float d = sqrtf(fmaxf(d2, 0.0f) + 1e-12f);
                __half hd = __float2half(d);
                tile[rl * 136 + cl] = hd;
                unsigned key = ((unsigned)__half_as_ushort(hd) << 16) | (unsigned)cglob;
                if (cglob == rglob) key = INF32;   // exclude self
                best = best < key ? best : key;
            }
            // min across the 16 lanes (lr) sharing this row
            #pragma unroll
            for (int off2 = 1; off2 < 16; off2 <<= 1) {
                unsigned o = __shfl_xor(best, off2);
                best = best < o ? best : o;
            }
            if (lr == 0)
                atomicMin(&compbest[rglob], make_key64(best, (unsigned)rglob));
        }
    }
    __syncthreads();

    // coalesced write-out: 16B/lane contiguous
    const int tileRow0 = I * 128;
    #pragma unroll
    for (int it = 0; it < 8; ++it) {
        int idx = it * 256 + t;
        int row = idx >> 4;
        int ch = idx & 15;
        *(uint4*)(&D[(size_t)(tileRow0 + row) * NPT + J * 128 + ch * 8]) =
            *(const uint4*)(&tile[row * 136 + ch * 8]);
    }
}

// ---------------- Boruvka phase A: 2 nodes per wave (doubled bytes in flight) ----------------
// grid (NPT/32, 2), block 1024 (16 waves x 2 rows)
__global__ __launch_bounds__(1024) void boruvka_a2(const __half* __restrict__ Dall,
                                                   const unsigned* __restrict__ compAll,
                                                   unsigned long long* __restrict__ compbestAll,
                                                   const unsigned* __restrict__ cnt) {
    const int mat = blockIdx.y;
    if (cnt[mat] >= NPT - 1u) return;                 // MST complete: no-op round
    const __half* __restrict__ D = Dall + (size_t)mat * NPT * NPT;
    const unsigned* __restrict__ comp = compAll + mat * NPT;
    unsigned long long* __restrict__ compbest = compbestAll + mat * NPT;

    __shared__ unsigned short lcomp[NPT];
    const int t = threadIdx.x;
    for (int i = t; i < NPT; i += 1024) lcomp[i] = (unsigned short)comp[i];
    __syncthreads();

    const int wv = t >> 6, ln = t & 63;
    const int node0 = blockIdx.x * 32 + wv * 2;
    const int node1 = node0 + 1;
    const unsigned ci0 = lcomp[node0];
    const unsigned ci1 = lcomp[node1];
    const unsigned* __restrict__ row0 = (const unsigned*)(D + (size_t)node0 * NPT);
    const unsigned* __restrict__ row1 = row0 + (NPT / 2);

    unsigned best0 = INF32, best1 = INF32;
    #pragma unroll
    for (int k = 0; k < 8; ++k) {
        const int jb = k * 512 + ln * 8;
        uint4 dv0 = *(const uint4*)(row0 + (jb >> 1));
        uint4 dv1 = *(const uint4*)(row1 + (jb >> 1));
        uint4 cv = *(const uint4*)&lcomp[jb];
        const unsigned dp0[4] = {dv0.x, dv0.y, dv0.z, dv0.w};
        const unsigned dp1[4] = {dv1.x, dv1.y, dv1.z, dv1.w};
        const unsigned cp[4]  = {cv.x, cv.y, cv.z, cv.w};
        #pragma unroll
        for (int q = 0; q < 4; ++q) {
            int j0 = jb + q * 2;
            unsigned clo = cp[q] & 0xFFFFu, chi = cp[q] >> 16;
            unsigned k00 = (dp0[q] << 16) | (unsigned)j0;
            unsigned k01 = (dp0[q] & 0xFFFF0000u) | (unsigned)(j0 + 1);
            if (clo == ci0) k00 = INF32;
            if (chi == ci0) k01 = INF32;
            unsigned m0 = k00 < k01 ? k00 : k01;
            best0 = best0 < m0 ? best0 : m0;
            unsigned k10 = (dp1[q] << 16) | (unsigned)j0;
            unsigned k11 = (dp1[q] & 0xFFFF0000u) | (unsigned)(j0 + 1);
            if (clo == ci1) k10 = INF32;
            if (chi == ci1) k11 = INF32;
            unsigned m1 = k10 < k11 ? k10 : k11;
            best1 = best1 < m1 ? best1 : m1;
        }
    }
    #pragma unroll
    for (int off = 32; off > 0; off >>= 1) {
        unsigned o0 = __shfl_down(best0, off);
        best0 = best0 < o0 ? best0 : o0;
        unsigned o1 = __shfl_down(best1, off);
        best1 = best1 < o1 ? best1 : o1;
    }
    if (ln == 0) {
        if (best0 != INF32) atomicMin(&compbest[ci0], make_key64(best0, (unsigned)node0));
        if (best1 != INF32) atomicMin(&compbest[ci1], make_key64(best1, (unsigned)node1));
    }
}

// ---------------- Boruvka phase C+D: union, collect weights, pointer-jump, reset ----------------
__global__ __launch_bounds__(1024) void boruvka_cd(unsigned* __restrict__ compAll,
                                                   unsigned long long* __restrict__ compbestAll,
                                                   float* __restrict__ wAll,
                                                   unsigned* __restrict__ cntAll) {
    const int mat = blockIdx.x;
    if (cntAll[mat] >= NPT - 1u) return;
    unsigned* __restrict__ comp = compAll + mat * NPT;
    unsigned long long* __restrict__ compbest = compbestAll + mat * NPT;
    float* __restrict__ w = wAll + mat * NPT;
    unsigned* __restrict__ cnt = cntAll + mat;

    __shared__ unsigned short par[NPT];
    const int t = threadIdx.x;

    for (int c = t; c < NPT; c += 1024) {
        unsigned p = (unsigned)c;
        unsigned long long key = compbest[c];
        if (comp[c] == (unsigned)c && key != INF64) {
            unsigned jout = (unsigned)(key & 0xFFFFull);
            unsigned c2 = comp[jout];
            unsigned long long k2 = compbest[c2];
            bool mutual = (k2 >> 16) == (key >> 16);     // same undirected edge
            if (!mutual || (unsigned)c < c2) {
                unsigned short hb = (unsigned short)(key >> 48);
                float wv = fminf(__half2float(__ushort_as_half(hb)), 100.0f);
                unsigned slot = atomicAdd(cnt, 1u);
                w[slot] = wv;
            }
            p = (mutual && (unsigned)c < c2) ? (unsigned)c : c2;
        }
        par[c] = (unsigned short)p;
    }
    __syncthreads();

    for (int it = 0; it < 12; ++it) {
        unsigned short np[4];
        #pragma unroll
        for (int q = 0; q < 4; ++q) np[q] = par[par[t + q * 1024]];
        __syncthreads();
        #pragma unroll
        for (int q = 0; q < 4; ++q) par[t + q * 1024] = np[q];
        __syncthreads();
    }

    for (int c = t; c < NPT; c += 1024) {
        comp[c] = par[comp[c]];
        compbest[c] = INF64;
    }
}

// ---------------- sort one weight array per block (bitonic, LDS) ----------------
__global__ __launch_bounds__(1024) void sort_kernel(float* __restrict__ wAll) {
    float* __restrict__ w = wAll + blockIdx.x * NPT;
    __shared__ float s[NPT];
    const int t = threadIdx.x;
    for (int i = t; i < NPT; i += 1024) s[i] = w[i];
    __syncthreads();

    for (int k = 2; k <= NPT; k <<= 1) {
        for (int j = k >> 1; j > 0; j >>= 1) {
            for (int i = t; i < NPT; i += 1024) {
                int ixj = i ^ j;
                if (ixj > i) {
                    bool up = (i & k) == 0;
                    float a = s[i], b = s[ixj];
                    if ((a > b) == up) { s[i] = b; s[ixj] = a; }
                }
            }
            __syncthreads();
        }
    }
    for (int i = t; i < NPT; i += 1024) w[i] = s[i];
}

// ---------------- W1 diff-sum + combine ----------------
__global__ __launch_bounds__(1024) void final2_kernel(const float* __restrict__ w,
                                                      const float* __restrict__ rep,
                                                      float* __restrict__ out) {
    const int t = threadIdx.x;
    float loc = 0.f;
    for (int i = t; i < NPT; i += 1024) loc += fabsf(w[i] - w[NPT + i]);
    #pragma unroll
    for (int off = 32; off > 0; off >>= 1) loc += __shfl_down(loc, off);
    __shared__ float reds[16];
    int wv = t >> 6, ln = t & 63;
    if (ln == 0) reds[wv] = loc;
    __syncthreads();
    if (t == 0) {
        float tot = 0.f;
        #pragma unroll
        for (int i = 0; i < 16; ++i) tot += reds[i];
        out[0] = tot + rep[0] * (1.0f / (NPT * DM));
    }
}

extern "C" void kernel_launch(void* const* d_in, const int* in_sizes, int n_in,
                              void* d_out, int out_size, void* d_ws, size_t ws_size,
                              hipStream_t stream) {
    const float* x1 = (const float*)d_in[0];
    const float* x2 = (const float*)d_in[1];
    float* out = (float*)d_out;

    char* ws = (char*)d_ws;
    __half* D = (__half*)ws;                                           // 64 MB
    size_t off = (size_t)2 * NPT * NPT * sizeof(__half);
    _Float16* Xh = (_Float16*)(ws + off);                              // 2 MB
    off += (size_t)2 * NPT * DM * sizeof(_Float16);
    float* norms = (float*)(ws + off);                                 // 32 KB
    off += (size_t)2 * NPT * sizeof(float);
    unsigned long long* compbest = (unsigned long long*)(ws + off);    // 64 KB
    off += (size_t)2 * NPT * sizeof(unsigned long long);
    float* w = (float*)(ws + off);                                     // 32 KB
    off += (size_t)2 * NPT * sizeof(float);
    unsigned* comp = (unsigned*)(ws + off);                            // 32 KB
    off += (size_t)2 * NPT * sizeof(unsigned);
    unsigned* cnt = (unsigned*)(ws + off);                             // 8 B
    off += 2 * sizeof(unsigned);
    float* rep = (float*)(ws + off);

    init_kernel<<<2 * NPT / 256, 256, 0, stream>>>(comp, compbest, w, cnt, rep);

    prep_kernel<<<NPT / 4, 256, 0, stream>>>(x1, x2, Xh, norms, rep);

    gram_kernel<<<dim3(1024, 2), 256, 0, stream>>>(Xh, norms, D, compbest);

    boruvka_cd<<<2, 1024, 0, stream>>>(comp, compbest, w, cnt);      // round 0 merge

    for (int r = 1; r < ROUNDS; ++r) {
        boruvka_a2<<<dim3(NPT / 32, 2), 1024, 0, stream>>>(D, comp, compbest, cnt);
        boruvka_cd<<<2, 1024, 0, stream>>>(comp, compbest, w, cnt);
    }

    sort_kernel<<<2, 1024, 0, stream>>>(w);

    final2_kernel<<<1, 1024, 0, stream>>>(w, rep, out);
}

// Round 10
// 347.768 us; speedup vs baseline: 2.8648x; 1.0452x over previous
//
#include <hip/hip_runtime.h>
#include <hip/hip_fp16.h>

#define NPT 4096
#define DM 128
#define ROUNDS 12
#define INF64 0xFFFFFFFFFFFFFFFFull
#define INF32 0xFFFFFFFFu

typedef _Float16 f16x8 __attribute__((ext_vector_type(8)));
typedef _Float16 f16x2 __attribute__((ext_vector_type(2)));
typedef float f32x4 __attribute__((ext_vector_type(4)));

static __device__ __forceinline__ unsigned long long make_key64(unsigned key, unsigned node) {
    unsigned h = key >> 16, j = key & 0xFFFFu;
    unsigned mn = node < j ? node : j;
    unsigned mx = node < j ? j : node;
    return ((unsigned long long)h << 48) | ((unsigned long long)mn << 32) |
           ((unsigned long long)mx << 16) | (unsigned long long)j;
}

// ---------------- init ----------------
__global__ __launch_bounds__(256) void init_kernel(unsigned* __restrict__ comp,
                                                   unsigned long long* __restrict__ compbest,
                                                   float* __restrict__ w,
                                                   unsigned* __restrict__ cnt,
                                                   float* __restrict__ rep) {
    int i = blockIdx.x * blockDim.x + threadIdx.x;   // 0..8191
    comp[i] = (unsigned)(i & (NPT - 1));
    compbest[i] = INF64;
    w[i] = 0.0f;
    if (i < 2) cnt[i] = 0u;
    if (i == 0) rep[0] = 0.0f;
}

// ---------------- prep: fp32 -> fp16 rows + consistent norms + rep-loss partials ----------------
__global__ __launch_bounds__(256) void prep_kernel(const float* __restrict__ x1,
                                                   const float* __restrict__ x2,
                                                   _Float16* __restrict__ Xh,
                                                   float* __restrict__ norms,
                                                   float* __restrict__ rep) {
    const int wv = threadIdx.x >> 6, ln = threadIdx.x & 63;
    const int row = blockIdx.x * 4 + wv;             // 0..4095
    float2 v1 = *(const float2*)(x1 + (size_t)row * DM + ln * 2);
    float2 v2 = *(const float2*)(x2 + (size_t)row * DM + ln * 2);
    _Float16 a0 = (_Float16)v1.x, a1 = (_Float16)v1.y;
    _Float16 b0 = (_Float16)v2.x, b1 = (_Float16)v2.y;
    f16x2 pa; pa[0] = a0; pa[1] = a1;
    f16x2 pb; pb[0] = b0; pb[1] = b1;
    *(f16x2*)(Xh + (size_t)row * DM + ln * 2) = pa;
    *(f16x2*)(Xh + (size_t)(NPT + row) * DM + ln * 2) = pb;

    float s1 = (float)a0 * (float)a0 + (float)a1 * (float)a1;
    float s2 = (float)b0 * (float)b0 + (float)b1 * (float)b1;
    float dx = v1.x - v2.x, dy = v1.y - v2.y;
    float rs = dx * dx + dy * dy;
    #pragma unroll
    for (int off = 32; off > 0; off >>= 1) {
        s1 += __shfl_down(s1, off);
        s2 += __shfl_down(s2, off);
        rs += __shfl_down(rs, off);
    }
    __shared__ float partial[4];
    if (ln == 0) {
        norms[row] = s1;
        norms[NPT + row] = s2;
        partial[wv] = rs;
    }
    __syncthreads();
    if (threadIdx.x == 0)
        atomicAdd(rep, partial[0] + partial[1] + partial[2] + partial[3]);
}

// ---------------- Gram via fp16 MFMA + fused exact 1-NN via LDS keybuf ----------------
// grid (1024, 2), block 256
__global__ __launch_bounds__(256) void gram_kernel(const _Float16* __restrict__ Xh,
                                                   const float* __restrict__ norms,
                                                   __half* __restrict__ Dall,
                                                   unsigned long long* __restrict__ compbestAll) {
    const int mat = blockIdx.y;
    const _Float16* __restrict__ X = Xh + (size_t)mat * NPT * DM;
    const float* __restrict__ nrm = norms + mat * NPT;
    __half* __restrict__ D = Dall + (size_t)mat * NPT * NPT;
    unsigned long long* __restrict__ compbest = compbestAll + mat * NPT;

    const int I = blockIdx.x >> 5;
    const int J = blockIdx.x & 31;

    __shared__ __half tile[128 * 136];       // rows 272B (16B-aligned)
    __shared__ unsigned keybuf[128 * 33];    // per-row 32 candidate mins (2 col-halves x 16 lanes)

    const int t = threadIdx.x;
    const int wv = t >> 6, ln = t & 63;
    const int rloc = (wv >> 1) * 64;
    const int cloc = (wv & 1) * 64;
    const int rowBase = I * 128 + rloc;
    const int colBase = J * 128 + cloc;
    const int lr = ln & 15;
    const int kg = ln >> 4;

    f32x4 acc[4][4];
    #pragma unroll
    for (int m = 0; m < 4; ++m)
        #pragma unroll
        for (int n = 0; n < 4; ++n)
            acc[m][n] = (f32x4){0.f, 0.f, 0.f, 0.f};

    #pragma unroll
    for (int ks = 0; ks < 4; ++ks) {
        const int k0 = ks * 32 + kg * 8;
        f16x8 a[4], b[4];
        #pragma unroll
        for (int m = 0; m < 4; ++m)
            a[m] = *(const f16x8*)(X + (size_t)(rowBase + m * 16 + lr) * DM + k0);
        #pragma unroll
        for (int n = 0; n < 4; ++n)
            b[n] = *(const f16x8*)(X + (size_t)(colBase + n * 16 + lr) * DM + k0);
        #pragma unroll
        for (int m = 0; m < 4; ++m)
            #pragma unroll
            for (int n = 0; n < 4; ++n)
                acc[m][n] = __builtin_amdgcn_mfma_f32_16x16x32_f16(a[m], b[n], acc[m][n], 0, 0, 0);
    }

    float nr[16], nc[4];
    #pragma unroll
    for (int m = 0; m < 4; ++m)
        #pragma unroll
        for (int q = 0; q < 4; ++q)
            nr[m * 4 + q] = nrm[rowBase + m * 16 + kg * 4 + q];
    #pragma unroll
    for (int n = 0; n < 4; ++n) nc[n] = nrm[colBase + n * 16 + lr];

    // C/D layout: col = lane&15, row = (lane>>4)*4 + reg
    #pragma unroll
    for (int m = 0; m < 4; ++m) {
        #pragma unroll
        for (int q = 0; q < 4; ++q) {
            const int rl = rloc + m * 16 + kg * 4 + q;
            const int rglob = I * 128 + rl;
            unsigned best = INF32;
            #pragma unroll
            for (int n = 0; n < 4; ++n) {
                const int cl = cloc + n * 16 + lr;
                const int cglob = J * 128 + cl;
                float d2 = nr[m * 4 + q] + nc[n] - 2.0f * acc[m][n][q];
                float d = sqrtf(fmaxf(d2, 0.0f) + 1e-12f);
                __half hd = __float2half(d);
                tile[rl * 136 + cl] = hd;
                unsigned key = ((unsigned)__half_as_ushort(hd) << 16) | (unsigned)cglob;
                if (cglob == rglob) key = INF32;   // exclude self
                best = best < key ? best : key;
            }
            keybuf[rl * 33 + (wv & 1) * 16 + lr] = best;   // lane-private slot, no shuffles
        }
    }
    __syncthreads();

    // row-min pass: 2 threads per row over 32 keybuf slots, then one shfl + atomicMin
    {
        const int r = t >> 1, h = t & 1;
        unsigned best = INF32;
        #pragma unroll
        for (int i = 0; i < 16; ++i) {
            unsigned k = keybuf[r * 33 + h * 16 + i];
            best = best < k ? best : k;
        }
        unsigned o = __shfl_xor(best, 1);
        best = best < o ? best : o;
        if (h == 0 && best != INF32)
            atomicMin(&compbest[I * 128 + r], make_key64(best, (unsigned)(I * 128 + r)));
    }

    // coalesced write-out: 16B/lane contiguous
    const int tileRow0 = I * 128;
    #pragma unroll
    for (int it = 0; it < 8; ++it) {
        int idx = it * 256 + t;
        int row = idx >> 4;
        int ch = idx & 15;
        *(uint4*)(&D[(size_t)(tileRow0 + row) * NPT + J * 128 + ch * 8]) =
            *(const uint4*)(&tile[row * 136 + ch * 8]);
    }
}

// ---------------- Boruvka phase A: 2 nodes/wave, full-row register prefetch ----------------
// grid (NPT/32, 2), block 1024 (16 waves x 2 rows)
__global__ __launch_bounds__(1024) void boruvka_a2(const __half* __restrict__ Dall,
                                                   const unsigned* __restrict__ compAll,
                                                   unsigned long long* __restrict__ compbestAll,
                                                   const unsigned* __restrict__ cnt) {
    const int mat = blockIdx.y;
    if (cnt[mat] >= NPT - 1u) return;                 // MST complete: no-op round
    const __half* __restrict__ D = Dall + (size_t)mat * NPT * NPT;
    const unsigned* __restrict__ comp = compAll + mat * NPT;
    unsigned long long* __restrict__ compbest = compbestAll + mat * NPT;

    __shared__ unsigned short lcomp[NPT];
    const int t = threadIdx.x;
    for (int i = t; i < NPT; i += 1024) lcomp[i] = (unsigned short)comp[i];
    __syncthreads();

    const int wv = t >> 6, ln = t & 63;
    const int node0 = blockIdx.x * 32 + wv * 2;
    const int node1 = node0 + 1;
    const unsigned ci0 = lcomp[node0];
    const unsigned ci1 = lcomp[node1];
    const uint4* __restrict__ row0 = (const uint4*)(D + (size_t)node0 * NPT);  // 512 uint4/row
    const uint4* __restrict__ row1 = (const uint4*)(D + (size_t)node1 * NPT);

    // prefetch: 16 independent 16B loads (256B/lane in flight)
    uint4 d0[8], d1[8];
    #pragma unroll
    for (int k = 0; k < 8; ++k) d0[k] = row0[k * 64 + ln];
    #pragma unroll
    for (int k = 0; k < 8; ++k) d1[k] = row1[k * 64 + ln];

    unsigned best0 = INF32, best1 = INF32;
    #pragma unroll
    for (int k = 0; k < 8; ++k) {
        const int jb = (k * 64 + ln) * 8;
        uint4 cv = *(const uint4*)&lcomp[jb];
        const unsigned dp0[4] = {d0[k].x, d0[k].y, d0[k].z, d0[k].w};
        const unsigned dp1[4] = {d1[k].x, d1[k].y, d1[k].z, d1[k].w};
        const unsigned cp[4]  = {cv.x, cv.y, cv.z, cv.w};
        #pragma unroll
        for (int q = 0; q < 4; ++q) {
            int j0 = jb + q * 2;
            unsigned clo = cp[q] & 0xFFFFu, chi = cp[q] >> 16;
            unsigned k00 = (dp0[q] << 16) | (unsigned)j0;
            unsigned k01 = (dp0[q] & 0xFFFF0000u) | (unsigned)(j0 + 1);
            if (clo == ci0) k00 = INF32;
            if (chi == ci0) k01 = INF32;
            unsigned m0 = k00 < k01 ? k00 : k01;
            best0 = best0 < m0 ? best0 : m0;
            unsigned k10 = (dp1[q] << 16) | (unsigned)j0;
            unsigned k11 = (dp1[q] & 0xFFFF0000u) | (unsigned)(j0 + 1);
            if (clo == ci1) k10 = INF32;
            if (chi == ci1) k11 = INF32;
            unsigned m1 = k10 < k11 ? k10 : k11;
            best1 = best1 < m1 ? best1 : m1;
        }
    }
    #pragma unroll
    for (int off = 32; off > 0; off >>= 1) {
        unsigned o0 = __shfl_down(best0, off);
        best0 = best0 < o0 ? best0 : o0;
        unsigned o1 = __shfl_down(best1, off);
        best1 = best1 < o1 ? best1 : o1;
    }
    if (ln == 0) {
        if (best0 != INF32) atomicMin(&compbest[ci0], make_key64(best0, (unsigned)node0));
        if (best1 != INF32) atomicMin(&compbest[ci1], make_key64(best1, (unsigned)node1));
    }
}

// ---------------- Boruvka phase C+D: union, collect weights, pointer-jump, reset ----------------
__global__ __launch_bounds__(1024) void boruvka_cd(unsigned* __restrict__ compAll,
                                                   unsigned long long* __restrict__ compbestAll,
                                                   float* __restrict__ wAll,
                                                   unsigned* __restrict__ cntAll) {
    const int mat = blockIdx.x;
    if (cntAll[mat] >= NPT - 1u) return;
    unsigned* __restrict__ comp = compAll + mat * NPT;
    unsigned long long* __restrict__ compbest = compbestAll + mat * NPT;
    float* __restrict__ w = wAll + mat * NPT;
    unsigned* __restrict__ cnt = cntAll + mat;

    __shared__ unsigned short par[NPT];
    const int t = threadIdx.x;

    for (int c = t; c < NPT; c += 1024) {
        unsigned p = (unsigned)c;
        unsigned long long key = compbest[c];
        if (comp[c] == (unsigned)c && key != INF64) {
            unsigned jout = (unsigned)(key & 0xFFFFull);
            unsigned c2 = comp[jout];
            unsigned long long k2 = compbest[c2];
            bool mutual = (k2 >> 16) == (key >> 16);     // same undirected edge
            if (!mutual || (unsigned)c < c2) {
                unsigned short hb = (unsigned short)(key >> 48);
                float wv = fminf(__half2float(__ushort_as_half(hb)), 100.0f);
                unsigned slot = atomicAdd(cnt, 1u);
                w[slot] = wv;
            }
            p = (mutual && (unsigned)c < c2) ? (unsigned)c : c2;
        }
        par[c] = (unsigned short)p;
    }
    __syncthreads();

    for (int it = 0; it < 12; ++it) {
        unsigned short np[4];
        #pragma unroll
        for (int q = 0; q < 4; ++q) np[q] = par[par[t + q * 1024]];
        __syncthreads();
        #pragma unroll
        for (int q = 0; q < 4; ++q) par[t + q * 1024] = np[q];
        __syncthreads();
    }

    for (int c = t; c < NPT; c += 1024) {
        comp[c] = par[comp[c]];
        compbest[c] = INF64;
    }
}

// ---------------- sort one weight array per block (bitonic, LDS) ----------------
__global__ __launch_bounds__(1024) void sort_kernel(float* __restrict__ wAll) {
    float* __restrict__ w = wAll + blockIdx.x * NPT;
    __shared__ float s[NPT];
    const int t = threadIdx.x;
    for (int i = t; i < NPT; i += 1024) s[i] = w[i];
    __syncthreads();

    for (int k = 2; k <= NPT; k <<= 1) {
        for (int j = k >> 1; j > 0; j >>= 1) {
            for (int i = t; i < NPT; i += 1024) {
                int ixj = i ^ j;
                if (ixj > i) {
                    bool up = (i & k) == 0;
                    float a = s[i], b = s[ixj];
                    if ((a > b) == up) { s[i] = b; s[ixj] = a; }
                }
            }
            __syncthreads();
        }
    }
    for (int i = t; i < NPT; i += 1024) w[i] = s[i];
}

// ---------------- W1 diff-sum + combine ----------------
__global__ __launch_bounds__(1024) void final2_kernel(const float* __restrict__ w,
                                                      const float* __restrict__ rep,
                                                      float* __restrict__ out) {
    const int t = threadIdx.x;
    float loc = 0.f;
    for (int i = t; i < NPT; i += 1024) loc += fabsf(w[i] - w[NPT + i]);
    #pragma unroll
    for (int off = 32; off > 0; off >>= 1) loc += __shfl_down(loc, off);
    __shared__ float reds[16];
    int wv = t >> 6, ln = t & 63;
    if (ln == 0) reds[wv] = loc;
    __syncthreads();
    if (t == 0) {
        float tot = 0.f;
        #pragma unroll
        for (int i = 0; i < 16; ++i) tot += reds[i];
        out[0] = tot + rep[0] * (1.0f / (NPT * DM));
    }
}

extern "C" void kernel_launch(void* const* d_in, const int* in_sizes, int n_in,
                              void* d_out, int out_size, void* d_ws, size_t ws_size,
                              hipStream_t stream) {
    const float* x1 = (const float*)d_in[0];
    const float* x2 = (const float*)d_in[1];
    float* out = (float*)d_out;

    char* ws = (char*)d_ws;
    __half* D = (__half*)ws;                                           // 64 MB
    size_t off = (size_t)2 * NPT * NPT * sizeof(__half);
    _Float16* Xh = (_Float16*)(ws + off);                              // 2 MB
    off += (size_t)2 * NPT * DM * sizeof(_Float16);
    float* norms = (float*)(ws + off);                                 // 32 KB
    off += (size_t)2 * NPT * sizeof(float);
    unsigned long long* compbest = (unsigned long long*)(ws + off);    // 64 KB
    off += (size_t)2 * NPT * sizeof(unsigned long long);
    float* w = (float*)(ws + off);                                     // 32 KB
    off += (size_t)2 * NPT * sizeof(float);
    unsigned* comp = (unsigned*)(ws + off);                            // 32 KB
    off += (size_t)2 * NPT * sizeof(unsigned);
    unsigned* cnt = (unsigned*)(ws + off);                             // 8 B
    off += 2 * sizeof(unsigned);
    float* rep = (float*)(ws + off);

    init_kernel<<<2 * NPT / 256, 256, 0, stream>>>(comp, compbest, w, cnt, rep);

    prep_kernel<<<NPT / 4, 256, 0, stream>>>(x1, x2, Xh, norms, rep);

    gram_kernel<<<dim3(1024, 2), 256, 0, stream>>>(Xh, norms, D, compbest);

    boruvka_cd<<<2, 1024, 0, stream>>>(comp, compbest, w, cnt);      // round 0 merge

    for (int r = 1; r < ROUNDS; ++r) {
        boruvka_a2<<<dim3(NPT / 32, 2), 1024, 0, stream>>>(D, comp, compbest, cnt);
        boruvka_cd<<<2, 1024, 0, stream>>>(comp, compbest, w, cnt);
    }

    sort_kernel<<<2, 1024, 0, stream>>>(w);

    final2_kernel<<<1, 1024, 0, stream>>>(w, rep, out);
}

// Round 11
// 342.111 us; speedup vs baseline: 2.9122x; 1.0165x over previous
//
#include <hip/hip_runtime.h>
#include <hip/hip_fp16.h>

#define NPT 4096
#define DM 128
#define INF64 0xFFFFFFFFFFFFFFFFull
#define INF32 0xFFFFFFFFu

typedef _Float16 f16x8 __attribute__((ext_vector_type(8)));
typedef _Float16 f16x2 __attribute__((ext_vector_type(2)));
typedef float f32x4 __attribute__((ext_vector_type(4)));

static __device__ __forceinline__ unsigned long long make_key64(unsigned key, unsigned node) {
    unsigned h = key >> 16, j = key & 0xFFFFu;
    unsigned mn = node < j ? node : j;
    unsigned mx = node < j ? j : node;
    return ((unsigned long long)h << 48) | ((unsigned long long)mn << 32) |
           ((unsigned long long)mx << 16) | (unsigned long long)j;
}

// streaming update of (K1,C1,K2,C2): best key + best key to a comp != C1. Exact.
#define UPD(K1, C1, K2, C2, kk, cc)                                   \
    do {                                                              \
        unsigned _k = (kk), _c = (cc);                                \
        if (_k < K1) {                                                \
            if (_c != C1) { K2 = K1; C2 = C1; }                       \
            K1 = _k; C1 = _c;                                         \
        } else if (_k < K2 && _c != C1) { K2 = _k; C2 = _c; }         \
    } while (0)

// ---------------- init ----------------
__global__ __launch_bounds__(256) void init_kernel(unsigned* __restrict__ comp,
                                                   unsigned long long* __restrict__ compbest,
                                                   float* __restrict__ w,
                                                   unsigned* __restrict__ cnt,
                                                   float* __restrict__ rep) {
    int i = blockIdx.x * blockDim.x + threadIdx.x;   // 0..8191
    comp[i] = (unsigned)(i & (NPT - 1));
    compbest[i] = INF64;
    w[i] = 0.0f;
    if (i < 2) cnt[i] = 0u;
    if (i == 0) rep[0] = 0.0f;
}

// ---------------- prep: fp32 -> fp16 rows + consistent norms + rep-loss partials ----------------
__global__ __launch_bounds__(256) void prep_kernel(const float* __restrict__ x1,
                                                   const float* __restrict__ x2,
                                                   _Float16* __restrict__ Xh,
                                                   float* __restrict__ norms,
                                                   float* __restrict__ rep) {
    const int wv = threadIdx.x >> 6, ln = threadIdx.x & 63;
    const int row = blockIdx.x * 4 + wv;             // 0..4095
    float2 v1 = *(const float2*)(x1 + (size_t)row * DM + ln * 2);
    float2 v2 = *(const float2*)(x2 + (size_t)row * DM + ln * 2);
    _Float16 a0 = (_Float16)v1.x, a1 = (_Float16)v1.y;
    _Float16 b0 = (_Float16)v2.x, b1 = (_Float16)v2.y;
    f16x2 pa; pa[0] = a0; pa[1] = a1;
    f16x2 pb; pb[0] = b0; pb[1] = b1;
    *(f16x2*)(Xh + (size_t)row * DM + ln * 2) = pa;
    *(f16x2*)(Xh + (size_t)(NPT + row) * DM + ln * 2) = pb;

    float s1 = (float)a0 * (float)a0 + (float)a1 * (float)a1;
    float s2 = (float)b0 * (float)b0 + (float)b1 * (float)b1;
    float dx = v1.x - v2.x, dy = v1.y - v2.y;
    float rs = dx * dx + dy * dy;
    #pragma unroll
    for (int off = 32; off > 0; off >>= 1) {
        s1 += __shfl_down(s1, off);
        s2 += __shfl_down(s2, off);
        rs += __shfl_down(rs, off);
    }
    __shared__ float partial[4];
    if (ln == 0) {
        norms[row] = s1;
        norms[NPT + row] = s2;
        partial[wv] = rs;
    }
    __syncthreads();
    if (threadIdx.x == 0)
        atomicAdd(rep, partial[0] + partial[1] + partial[2] + partial[3]);
}

// ---------------- Gram via fp16 MFMA; emits per-(row,tile) top-2 into G ----------------
// grid (1024, 2), block 256
__global__ __launch_bounds__(256) void gram_kernel(const _Float16* __restrict__ Xh,
                                                   const float* __restrict__ norms,
                                                   __half* __restrict__ Dall,
                                                   unsigned* __restrict__ Gall) {
    const int mat = blockIdx.y;
    const _Float16* __restrict__ X = Xh + (size_t)mat * NPT * DM;
    const float* __restrict__ nrm = norms + mat * NPT;
    __half* __restrict__ D = Dall + (size_t)mat * NPT * NPT;
    unsigned* __restrict__ G = Gall + (size_t)mat * NPT * 64;

    const int I = blockIdx.x >> 5;
    const int J = blockIdx.x & 31;

    __shared__ __half tile[128 * 136];       // rows 272B
    __shared__ unsigned keybuf[128 * 66];    // per row: 32 b-slots [0..31], 32 s-slots [33..64]

    const int t = threadIdx.x;
    const int wv = t >> 6, ln = t & 63;
    const int rloc = (wv >> 1) * 64;
    const int cloc = (wv & 1) * 64;
    const int rowBase = I * 128 + rloc;
    const int colBase = J * 128 + cloc;
    const int lr = ln & 15;
    const int kg = ln >> 4;

    f32x4 acc[4][4];
    #pragma unroll
    for (int m = 0; m < 4; ++m)
        #pragma unroll
        for (int n = 0; n < 4; ++n)
            acc[m][n] = (f32x4){0.f, 0.f, 0.f, 0.f};

    #pragma unroll
    for (int ks = 0; ks < 4; ++ks) {
        const int k0 = ks * 32 + kg * 8;
        f16x8 a[4], b[4];
        #pragma unroll
        for (int m = 0; m < 4; ++m)
            a[m] = *(const f16x8*)(X + (size_t)(rowBase + m * 16 + lr) * DM + k0);
        #pragma unroll
        for (int n = 0; n < 4; ++n)
            b[n] = *(const f16x8*)(X + (size_t)(colBase + n * 16 + lr) * DM + k0);
        #pragma unroll
        for (int m = 0; m < 4; ++m)
            #pragma unroll
            for (int n = 0; n < 4; ++n)
                acc[m][n] = __builtin_amdgcn_mfma_f32_16x16x32_f16(a[m], b[n], acc[m][n], 0, 0, 0);
    }

    float nr[16], nc[4];
    #pragma unroll
    for (int m = 0; m < 4; ++m)
        #pragma unroll
        for (int q = 0; q < 4; ++q)
            nr[m * 4 + q] = nrm[rowBase + m * 16 + kg * 4 + q];
    #pragma unroll
    for (int n = 0; n < 4; ++n) nc[n] = nrm[colBase + n * 16 + lr];

    // C/D layout: col = lane&15, row = (lane>>4)*4 + reg
    #pragma unroll
    for (int m = 0; m < 4; ++m) {
        #pragma unroll
        for (int q = 0; q < 4; ++q) {
            const int rl = rloc + m * 16 + kg * 4 + q;
            const int rglob = I * 128 + rl;
            unsigned b = INF32, s = INF32;
            #pragma unroll
            for (int n = 0; n < 4; ++n) {
                const int cl = cloc + n * 16 + lr;
                const int cglob = J * 128 + cl;
                float d2 = nr[m * 4 + q] + nc[n] - 2.0f * acc[m][n][q];
                float d = sqrtf(fmaxf(d2, 0.0f) + 1e-12f);
                __half hd = __float2half(d);
                tile[rl * 136 + cl] = hd;
                unsigned key = ((unsigned)__half_as_ushort(hd) << 16) | (unsigned)cglob;
                if (cglob == rglob) key = INF32;   // exclude self
                if (key < b) { s = b; b = key; } else if (key < s) s = key;
            }
            keybuf[rl * 66 + (wv & 1) * 16 + lr] = b;
            keybuf[rl * 66 + 33 + (wv & 1) * 16 + lr] = s;
        }
    }
    __syncthreads();

    // per-row top-2 over 32 (b,s) slots -> G[row][J*2 .. J*2+1]
    {
        const int r = t >> 1, h = t & 1;
        unsigned B = INF32, S = INF32;
        #pragma unroll
        for (int i = 0; i < 16; ++i) {
            unsigned k = keybuf[r * 66 + h * 16 + i];
            if (k < B) { S = B; B = k; } else if (k < S) S = k;
        }
        #pragma unroll
        for (int i = 0; i < 16; ++i) {
            unsigned k = keybuf[r * 66 + 33 + h * 16 + i];
            if (k < B) { S = B; B = k; } else if (k < S) S = k;
        }
        unsigned oB = __shfl_xor(B, 1), oS = __shfl_xor(S, 1);
        unsigned wn = B < oB ? B : oB;
        unsigned ls = B < oB ? oB : B;
        unsigned ws = B < oB ? S : oS;
        B = wn; S = ls < ws ? ls : ws;
        if (h == 0) {
            G[(size_t)(I * 128 + r) * 64 + J * 2] = B;
            G[(size_t)(I * 128 + r) * 64 + J * 2 + 1] = S;
        }
    }
    __syncthreads();

    // coalesced D write-out
    const int tileRow0 = I * 128;
    #pragma unroll
    for (int it = 0; it < 8; ++it) {
        int idx = it * 256 + t;
        int row = idx >> 4;
        int ch = idx & 15;
        *(uint4*)(&D[(size_t)(tileRow0 + row) * NPT + J * 128 + ch * 8]) =
            *(const uint4*)(&tile[row * 136 + ch * 8]);
    }
}

// ---------------- reduce G -> per-node (best1,best2) + round-0 compbest ----------------
// grid (64, 2), block 1024: wave handles 4 rows
__global__ __launch_bounds__(1024) void greduce_kernel(const unsigned* __restrict__ Gall,
                                                       unsigned long long* __restrict__ compbestAll,
                                                       unsigned long long* __restrict__ bndAll) {
    const int mat = blockIdx.y;
    const unsigned* __restrict__ G = Gall + (size_t)mat * NPT * 64;
    unsigned long long* __restrict__ compbest = compbestAll + mat * NPT;
    unsigned long long* __restrict__ bnd = bndAll + mat * NPT;
    const int t = threadIdx.x, wv = t >> 6, ln = t & 63;
    #pragma unroll
    for (int rr = 0; rr < 4; ++rr) {
        const int row = blockIdx.x * 64 + wv * 4 + rr;
        unsigned B = G[(size_t)row * 64 + ln];
        unsigned S = INF32;
        #pragma unroll
        for (int off = 32; off > 0; off >>= 1) {
            unsigned oB = __shfl_down(B, off), oS = __shfl_down(S, off);
            unsigned wn = B < oB ? B : oB;
            unsigned ls = B < oB ? oB : B;
            unsigned ws = B < oB ? S : oS;
            B = wn;
            unsigned m2 = ls < ws ? ls : ws;
            S = m2;
        }
        if (ln == 0) {
            compbest[row] = make_key64(B, (unsigned)row);   // single writer, no atomic
            bnd[row] = ((unsigned long long)B << 32) | S;
        }
    }
}

// ---------------- full scan computing (best1, best2-distinct-comp) per node ----------------
// grid (NPT/32, 2), block 1024 (16 waves x 2 rows)
__global__ __launch_bounds__(1024) void scan_s2(const __half* __restrict__ Dall,
                                                const unsigned* __restrict__ compAll,
                                                unsigned long long* __restrict__ compbestAll,
                                                unsigned long long* __restrict__ bndAll,
                                                const unsigned* __restrict__ cnt) {
    const int mat = blockIdx.y;
    if (cnt[mat] >= NPT - 1u) return;
    const __half* __restrict__ D = Dall + (size_t)mat * NPT * NPT;
    const unsigned* __restrict__ comp = compAll + mat * NPT;
    unsigned long long* __restrict__ compbest = compbestAll + mat * NPT;
    unsigned long long* __restrict__ bnd = bndAll + mat * NPT;

    __shared__ unsigned short lcomp[NPT];
    const int t = threadIdx.x;
    for (int i = t; i < NPT; i += 1024) lcomp[i] = (unsigned short)comp[i];
    __syncthreads();

    const int wv = t >> 6, ln = t & 63;
    const int node0 = blockIdx.x * 32 + wv * 2;
    const int node1 = node0 + 1;
    const unsigned ci0 = lcomp[node0];
    const unsigned ci1 = lcomp[node1];
    const uint4* __restrict__ row0 = (const uint4*)(D + (size_t)node0 * NPT);
    const uint4* __restrict__ row1 = (const uint4*)(D + (size_t)node1 * NPT);

    unsigned K1a = INF32, C1a = 0xFFFFu, K2a = INF32, C2a = 0xFFFFu;
    unsigned K1b = INF32, C1b = 0xFFFFu, K2b = INF32, C2b = 0xFFFFu;

    #pragma unroll
    for (int k = 0; k < 8; ++k) {
        uint4 d0 = row0[k * 64 + ln];
        uint4 d1 = row1[k * 64 + ln];
        const int jb = (k * 64 + ln) * 8;
        uint4 cv = *(const uint4*)&lcomp[jb];
        const unsigned dp0[4] = {d0.x, d0.y, d0.z, d0.w};
        const unsigned dp1[4] = {d1.x, d1.y, d1.z, d1.w};
        const unsigned cp[4]  = {cv.x, cv.y, cv.z, cv.w};
        #pragma unroll
        for (int q = 0; q < 4; ++q) {
            int j0 = jb + q * 2;
            unsigned clo = cp[q] & 0xFFFFu, chi = cp[q] >> 16;
            unsigned k00 = (dp0[q] << 16) | (unsigned)j0;
            unsigned k01 = (dp0[q] & 0xFFFF0000u) | (unsigned)(j0 + 1);
            if (clo == ci0) k00 = INF32;
            if (chi == ci0) k01 = INF32;
            UPD(K1a, C1a, K2a, C2a, k00, clo);
            UPD(K1a, C1a, K2a, C2a, k01, chi);
            unsigned k10 = (dp1[q] << 16) | (unsigned)j0;
            unsigned k11 = (dp1[q] & 0xFFFF0000u) | (unsigned)(j0 + 1);
            if (clo == ci1) k10 = INF32;
            if (chi == ci1) k11 = INF32;
            UPD(K1b, C1b, K2b, C2b, k10, clo);
            UPD(K1b, C1b, K2b, C2b, k11, chi);
        }
    }

    // wave-reduce the (K1,C1,K2,C2) summaries (exact merge)
    #pragma unroll
    for (int off = 32; off > 0; off >>= 1) {
        unsigned oK1, oC1, oK2, oC2, X, XC;
        oK1 = __shfl_down(K1a, off); oC1 = __shfl_down(C1a, off);
        oK2 = __shfl_down(K2a, off); oC2 = __shfl_down(C2a, off);
        if (oK1 < K1a) {
            X = (C1a != oC1) ? K1a : K2a; XC = (C1a != oC1) ? C1a : C2a;
            if (oK2 <= X) { K2a = oK2; C2a = oC2; } else { K2a = X; C2a = XC; }
            K1a = oK1; C1a = oC1;
        } else {
            X = (oC1 != C1a) ? oK1 : oK2; XC = (oC1 != C1a) ? oC1 : oC2;
            if (X < K2a) { K2a = X; C2a = XC; }
        }
        oK1 = __shfl_down(K1b, off); oC1 = __shfl_down(C1b, off);
        oK2 = __shfl_down(K2b, off); oC2 = __shfl_down(C2b, off);
        if (oK1 < K1b) {
            X = (C1b != oC1) ? K1b : K2b; XC = (C1b != oC1) ? C1b : C2b;
            if (oK2 <= X) { K2b = oK2; C2b = oC2; } else { K2b = X; C2b = XC; }
            K1b = oK1; C1b = oC1;
        } else {
            X = (oC1 != C1b) ? oK1 : oK2; XC = (oC1 != C1b) ? oC1 : oC2;
            if (X < K2b) { K2b = X; C2b = XC; }
        }
    }

    if (ln == 0) {
        if (K1a != INF32) atomicMin(&compbest[ci0], make_key64(K1a, (unsigned)node0));
        if (K1b != INF32) atomicMin(&compbest[ci1], make_key64(K1b, (unsigned)node1));
        bnd[node0] = ((unsigned long long)K1a << 32) | K2a;
        bnd[node1] = ((unsigned long long)K1b << 32) | K2b;
    }
}

// ---------------- paired round phase A from bnd, with exact grid-wide fallback ----------------
// grid (NPT/64, 2), block 1024: wave handles 4 nodes
__global__ __launch_bounds__(1024) void pairA(const __half* __restrict__ Dall,
                                              const unsigned* __restrict__ compAll,
                                              unsigned long long* __restrict__ compbestAll,
                                              const unsigned long long* __restrict__ bndAll,
                                              const unsigned* __restrict__ cnt) {
    const int mat = blockIdx.y;
    if (cnt[mat] >= NPT - 1u) return;
    const __half* __restrict__ D = Dall + (size_t)mat * NPT * NPT;
    const unsigned* __restrict__ comp = compAll + mat * NPT;
    unsigned long long* __restrict__ compbest = compbestAll + mat * NPT;
    const unsigned long long* __restrict__ bnd = bndAll + mat * NPT;

    __shared__ unsigned short lcomp[NPT];
    const int t = threadIdx.x;
    for (int i = t; i < NPT; i += 1024) lcomp[i] = (unsigned short)comp[i];
    __syncthreads();

    const int wv = t >> 6, ln = t & 63;
    #pragma unroll
    for (int rr = 0; rr < 4; ++rr) {
        const int node = blockIdx.x * 64 + wv * 4 + rr;
        const unsigned ci = lcomp[node];
        unsigned long long bv = bnd[node];
        unsigned K1 = (unsigned)(bv >> 32), K2 = (unsigned)bv;
        unsigned cand = INF32;
        bool fb = false;
        if (K1 != INF32) {
            unsigned c1 = lcomp[K1 & 0xFFFFu];
            if (c1 != ci) cand = K1;
            else if (K2 != INF32) {
                unsigned c2 = lcomp[K2 & 0xFFFFu];
                if (c2 != ci) cand = K2;
                else fb = true;
            }
            // K2==INF32: all scan-time foreign edges were one comp, now internal -> none left
        }
        if (cand != INF32) {
            if (ln == 0) atomicMin(&compbest[ci], make_key64(cand, (unsigned)node));
        } else if (fb) {
            // exact fallback: full row rescan by this wave
            const uint4* __restrict__ row = (const uint4*)(D + (size_t)node * NPT);
            unsigned best = INF32;
            #pragma unroll
            for (int k = 0; k < 8; ++k) {
                uint4 dv = row[k * 64 + ln];
                const int jb = (k * 64 + ln) * 8;
                uint4 cv = *(const uint4*)&lcomp[jb];
                const unsigned dp[4] = {dv.x, dv.y, dv.z, dv.w};
                const unsigned cp[4] = {cv.x, cv.y, cv.z, cv.w};
                #pragma unroll
                for (int q = 0; q < 4; ++q) {
                    int j0 = jb + q * 2;
                    unsigned k0 = (dp[q] << 16) | (unsigned)j0;
                    unsigned k1 = (dp[q] & 0xFFFF0000u) | (unsigned)(j0 + 1);
                    if ((cp[q] & 0xFFFFu) == ci) k0 = INF32;
                    if ((cp[q] >> 16) == ci)     k1 = INF32;
                    unsigned m = k0 < k1 ? k0 : k1;
                    best = best < m ? best : m;
                }
            }
            #pragma unroll
            for (int off = 32; off > 0; off >>= 1) {
                unsigned o = __shfl_down(best, off);
                best = best < o ? best : o;
            }
            if (ln == 0 && best != INF32)
                atomicMin(&compbest[ci], make_key64(best, (unsigned)node));
        }
    }
}

// ---------------- Boruvka phase C+D: union, collect weights, pointer-jump, reset ----------------
__global__ __launch_bounds__(1024) void boruvka_cd(unsigned* __restrict__ compAll,
                                                   unsigned long long* __restrict__ compbestAll,
                                                   float* __restrict__ wAll,
                                                   unsigned* __restrict__ cntAll) {
    const int mat = blockIdx.x;
    if (cntAll[mat] >= NPT - 1u) return;
    unsigned* __restrict__ comp = compAll + mat * NPT;
    unsigned long long* __restrict__ compbest = compbestAll + mat * NPT;
    float* __restrict__ w = wAll + mat * NPT;
    unsigned* __restrict__ cnt = cntAll + mat;

    __shared__ unsigned short par[NPT];
    const int t = threadIdx.x;

    for (int c = t; c < NPT; c += 1024) {
        unsigned p = (unsigned)c;
        unsigned long long key = compbest[c];
        if (comp[c] == (unsigned)c && key != INF64) {
            unsigned jout = (unsigned)(key & 0xFFFFull);
            unsigned c2 = comp[jout];
            unsigned long long k2 = compbest[c2];
            bool mutual = (k2 >> 16) == (key >> 16);     // same undirected edge
            if (!mutual || (unsigned)c < c2) {
                unsigned short hb = (unsigned short)(key >> 48);
                float wv = fminf(__half2float(__ushort_as_half(hb)), 100.0f);
                unsigned slot = atomicAdd(cnt, 1u);
                w[slot] = wv;
            }
            p = (mutual && (unsigned)c < c2) ? (unsigned)c : c2;
        }
        par[c] = (unsigned short)p;
    }
    __syncthreads();

    for (int it = 0; it < 12; ++it) {
        unsigned short np[4];
        #pragma unroll
        for (int q = 0; q < 4; ++q) np[q] = par[par[t + q * 1024]];
        __syncthreads();
        #pragma unroll
        for (int q = 0; q < 4; ++q) par[t + q * 1024] = np[q];
        __syncthreads();
    }

    for (int c = t; c < NPT; c += 1024) {
        comp[c] = par[comp[c]];
        compbest[c] = INF64;
    }
}

// ---------------- sort one weight array per block (bitonic, LDS) ----------------
__global__ __launch_bounds__(1024) void sort_kernel(float* __restrict__ wAll) {
    float* __restrict__ w = wAll + blockIdx.x * NPT;
    __shared__ float s[NPT];
    const int t = threadIdx.x;
    for (int i = t; i < NPT; i += 1024) s[i] = w[i];
    __syncthreads();

    for (int k = 2; k <= NPT; k <<= 1) {
        for (int j = k >> 1; j > 0; j >>= 1) {
            for (int i = t; i < NPT; i += 1024) {
                int ixj = i ^ j;
                if (ixj > i) {
                    bool up = (i & k) == 0;
                    float a = s[i], b = s[ixj];
                    if ((a > b) == up) { s[i] = b; s[ixj] = a; }
                }
            }
            __syncthreads();
        }
    }
    for (int i = t; i < NPT; i += 1024) w[i] = s[i];
}

// ---------------- W1 diff-sum + combine ----------------
__global__ __launch_bounds__(1024) void final2_kernel(const float* __restrict__ w,
                                                      const float* __restrict__ rep,
                                                      float* __restrict__ out) {
    const int t = threadIdx.x;
    float loc = 0.f;
    for (int i = t; i < NPT; i += 1024) loc += fabsf(w[i] - w[NPT + i]);
    #pragma unroll
    for (int off = 32; off > 0; off >>= 1) loc += __shfl_down(loc, off);
    __shared__ float reds[16];
    int wv = t >> 6, ln = t & 63;
    if (ln == 0) reds[wv] = loc;
    __syncthreads();
    if (t == 0) {
        float tot = 0.f;
        #pragma unroll
        for (int i = 0; i < 16; ++i) tot += reds[i];
        out[0] = tot + rep[0] * (1.0f / (NPT * DM));
    }
}

extern "C" void kernel_launch(void* const* d_in, const int* in_sizes, int n_in,
                              void* d_out, int out_size, void* d_ws, size_t ws_size,
                              hipStream_t stream) {
    const float* x1 = (const float*)d_in[0];
    const float* x2 = (const float*)d_in[1];
    float* out = (float*)d_out;

    char* ws = (char*)d_ws;
    __half* D = (__half*)ws;                                           // 64 MB
    size_t off = (size_t)2 * NPT * NPT * sizeof(__half);
    _Float16* Xh = (_Float16*)(ws + off);                              // 2 MB
    off += (size_t)2 * NPT * DM * sizeof(_Float16);
    float* norms = (float*)(ws + off);                                 // 32 KB
    off += (size_t)2 * NPT * sizeof(float);
    unsigned long long* compbest = (unsigned long long*)(ws + off);    // 64 KB
    off += (size_t)2 * NPT * sizeof(unsigned long long);
    unsigned long long* bnd = (unsigned long long*)(ws + off);         // 64 KB
    off += (size_t)2 * NPT * sizeof(unsigned long long);
    float* w = (float*)(ws + off);                                     // 32 KB
    off += (size_t)2 * NPT * sizeof(float);
    unsigned* comp = (unsigned*)(ws + off);                            // 32 KB
    off += (size_t)2 * NPT * sizeof(unsigned);
    unsigned* G = (unsigned*)(ws + off);                               // 2 MB
    off += (size_t)2 * NPT * 64 * sizeof(unsigned);
    unsigned* cnt = (unsigned*)(ws + off);                             // 8 B
    off += 2 * sizeof(unsigned);
    float* rep = (float*)(ws + off);

    init_kernel<<<2 * NPT / 256, 256, 0, stream>>>(comp, compbest, w, cnt, rep);

    prep_kernel<<<NPT / 4, 256, 0, stream>>>(x1, x2, Xh, norms, rep);

    gram_kernel<<<dim3(1024, 2), 256, 0, stream>>>(Xh, norms, D, G);

    // round 0: reduce G (best1 per node), merge
    greduce_kernel<<<dim3(NPT / 64, 2), 1024, 0, stream>>>(G, compbest, bnd);
    boruvka_cd<<<2, 1024, 0, stream>>>(comp, compbest, w, cnt);

    // round 1: paired round from gram's best2 (+ exact fallback)
    pairA<<<dim3(NPT / 64, 2), 1024, 0, stream>>>(D, comp, compbest, bnd, cnt);
    boruvka_cd<<<2, 1024, 0, stream>>>(comp, compbest, w, cnt);

    // rounds 2..11: scan covers round r, bnd covers round r+1
    for (int s = 0; s < 5; ++s) {
        scan_s2<<<dim3(NPT / 32, 2), 1024, 0, stream>>>(D, comp, compbest, bnd, cnt);
        boruvka_cd<<<2, 1024, 0, stream>>>(comp, compbest, w, cnt);
        pairA<<<dim3(NPT / 64, 2), 1024, 0, stream>>>(D, comp, compbest, bnd, cnt);
        boruvka_cd<<<2, 1024, 0, stream>>>(comp, compbest, w, cnt);
    }

    sort_kernel<<<2, 1024, 0, stream>>>(w);

    final2_kernel<<<1, 1024, 0, stream>>>(w, rep, out);
}